// Round 12
// baseline (146.286 us; speedup 1.0000x reference)
//
#include <hip/hip_runtime.h>

typedef __attribute__((ext_vector_type(8))) __bf16 bf16x8;
typedef __attribute__((ext_vector_type(4))) __bf16 bf16x4;
typedef __attribute__((ext_vector_type(4))) float f32x4;
typedef __attribute__((ext_vector_type(8))) _Float16 f16x8;

#define LOG2E 1.44269504088896340736f

__device__ __forceinline__ void async_load16(const void* g, void* l) {
  __builtin_amdgcn_global_load_lds(
      (const __attribute__((address_space(1))) void*)g,
      (__attribute__((address_space(3))) void*)l, 16, 0, 0);
}

__device__ __forceinline__ float fast_exp2(float x) {
#if __has_builtin(__builtin_amdgcn_exp2f)
  return __builtin_amdgcn_exp2f(x);
#else
  return __expf(x * 0.6931471805599453f);
#endif
}

// ---------------- fp32 -> bf16 convert, 3 segments in one launch ----------
__global__ void cvt3(const float* __restrict__ a, __bf16* __restrict__ oa, int na4,
                     const float* __restrict__ b, __bf16* __restrict__ ob, int nb4,
                     const float* __restrict__ c, __bf16* __restrict__ oc, int nc4) {
  int i = blockIdx.x * blockDim.x + threadIdx.x;
  int n = na4 + nb4 + nc4;
  int stride = gridDim.x * blockDim.x;
  for (; i < n; i += stride) {
    const float4* s;
    bf16x4* d;
    int j;
    if (i < na4) { s = (const float4*)a; d = (bf16x4*)oa; j = i; }
    else if (i < na4 + nb4) { s = (const float4*)b; d = (bf16x4*)ob; j = i - na4; }
    else { s = (const float4*)c; d = (bf16x4*)oc; j = i - na4 - nb4; }
    float4 v = s[j];
    bf16x4 o;
    o[0] = (__bf16)v.x; o[1] = (__bf16)v.y; o[2] = (__bf16)v.z; o[3] = (__bf16)v.w;
    d[j] = o;
  }
}

// ---------------- log2-domain bias table, per-lane fragment layout ----------
// ebT f16x8 index (((b*64+qt)*32+kt)*64 + lane); element [ni*4+r] =
//   (sigmoid(gbias[b][kt*32+16ni+ln][qt*16+4g+r]) - 0.5) * 10*alpha*log2e
__global__ __launch_bounds__(256) void build_ebias(
    const float* __restrict__ gbias, const float* __restrict__ bstr,
    _Float16* __restrict__ ebT) {
  const int gid = blockIdx.x * 256 + threadIdx.x;  // 4096 blocks
  const int lane = gid & 63;
  const int kt = (gid >> 6) & 31;
  const int qt = (gid >> 11) & 63;
  const int b = gid >> 17;
  const int g = lane >> 4, ln = lane & 15;
  const float alpha = 1.f / (1.f + __expf(-bstr[0]));
  const float bsc = 10.f * alpha * LOG2E;
  const float* base = gbias + (size_t)(b * 1024 + kt * 32 + ln) * 1024 + qt * 16 + g * 4;
  float4 va = *(const float4*)(base);                  // ni=0 row
  float4 vb = *(const float4*)(base + 16 * 1024);      // ni=1 row
  float sv[8] = {va.x, va.y, va.z, va.w, vb.x, vb.y, vb.z, vb.w};
  f16x8 o;
#pragma unroll
  for (int i = 0; i < 8; ++i)
    o[i] = (_Float16)((1.f / (1.f + __expf(-sv[i])) - 0.5f) * bsc);
  *(f16x8*)(ebT + (size_t)gid * 8) = o;
}

// ---------------- C = (A @ Bm^T + bias) [*scale] ----------------
template <int MODE>
__global__ __launch_bounds__(256) void gemm_bt(
    const __bf16* __restrict__ A, const __bf16* __restrict__ Bm,
    const float* __restrict__ bias, void* __restrict__ C0,
    __bf16* __restrict__ vT, int M, int N, int K) {
  __shared__ __align__(16) char smem[32768];
  char* lA = smem;
  char* lB = smem + 16384;
  const int t = threadIdx.x;
  const int lane = t & 63;
  const int wid = t >> 6;
  const int wm = wid >> 1, wn = wid & 1;
  const int g = lane >> 4, ln = lane & 15;
  const int m0 = blockIdx.y * 128;
  const int n0 = blockIdx.x * 128;

  const int srow = t >> 3;
  const int sswz = ((t & 7) * 16) ^ ((srow & 7) << 4);
  const size_t KB = (size_t)K * 2;
  const char* gA = (const char*)A + (size_t)m0 * KB;
  const char* gB = (const char*)Bm + (size_t)n0 * KB;

  f32x4 acc[4][4] = {};

  for (int k0 = 0; k0 < K; k0 += 64) {
    __syncthreads();
#pragma unroll
    for (int c = 0; c < 4; ++c) {
      int row = srow + 32 * c;
      async_load16(gA + (size_t)row * KB + k0 * 2 + sswz, lA + c * 4096 + t * 16);
      async_load16(gB + (size_t)row * KB + k0 * 2 + sswz, lB + c * 4096 + t * 16);
    }
    __syncthreads();
#pragma unroll
    for (int ks = 0; ks < 2; ++ks) {
      bf16x8 af[4], bf[4];
#pragma unroll
      for (int i = 0; i < 4; ++i) {
        int ar = wm * 64 + i * 16 + ln;
        int byo = (ks * 64 + g * 16) ^ ((ar & 7) << 4);
        af[i] = *(const bf16x8*)(lA + ar * 128 + byo);
        int br = wn * 64 + i * 16 + ln;
        bf[i] = *(const bf16x8*)(lB + br * 128 + byo);
      }
#pragma unroll
      for (int i = 0; i < 4; ++i)
#pragma unroll
        for (int j = 0; j < 4; ++j)
          acc[i][j] = __builtin_amdgcn_mfma_f32_16x16x32_bf16(af[i], bf[j], acc[i][j], 0, 0, 0);
    }
  }

#pragma unroll
  for (int j = 0; j < 4; ++j) {
    int col = n0 + wn * 64 + j * 16 + ln;
    float bv = bias[col];
    if (MODE == 0) {
#pragma unroll
      for (int i = 0; i < 4; ++i) {
        int row0 = m0 + wm * 64 + i * 16 + g * 4;
#pragma unroll
        for (int r = 0; r < 4; ++r)
          ((float*)C0)[(size_t)(row0 + r) * N + col] = acc[i][j][r] + bv;
      }
    } else if (col < 1024) {
      float scale = (col < 512) ? (0.125f * LOG2E) : 1.0f;
#pragma unroll
      for (int i = 0; i < 4; ++i) {
        int row0 = m0 + wm * 64 + i * 16 + g * 4;
#pragma unroll
        for (int r = 0; r < 4; ++r)
          ((__bf16*)C0)[(size_t)(row0 + r) * 1024 + col] = (__bf16)((acc[i][j][r] + bv) * scale);
      }
    } else {
      int h = (col - 1024) >> 6;
      int d = (col - 1024) & 63;
#pragma unroll
      for (int i = 0; i < 4; ++i) {
        int row0 = m0 + wm * 64 + i * 16 + g * 4;
        int b = row0 >> 10;
        bf16x4 pk;
#pragma unroll
        for (int r = 0; r < 4; ++r) pk[r] = (__bf16)(acc[i][j][r] + bv);
        *(bf16x4*)(vT + (((size_t)b * 8 + h) * 64 + d) * 1024 + (row0 & 1023)) = pk;
      }
    }
  }
}

// ---------------- fused flash attention: block-cooperative shared K/V -----
// 512 blocks = (b, h, qg): 8 waves = 8 q-tiles of ONE head. K/V staged
// cooperatively (1 gl_lds per wave per iter, 8x less than per-wave staging),
// double-buffered in shared LDS; eb per-wave register load. One barrier per
// iter; stage issued FIRST, drained LAST (whole compute in between). LDS
// 24.6KB/block -> 4 blocks/CU -> 32 waves/CU.
__global__ __launch_bounds__(512, 8) void attn_fused(
    const __bf16* __restrict__ qk,    // [B][N][1024]: q(log2-prescaled)|k
    const __bf16* __restrict__ vT,    // [B*8][64 d][1024 k]
    const _Float16* __restrict__ ebT, // f16 bias table
    __bf16* __restrict__ attn) {      // [B][N][512]
  __shared__ __align__(16) char smem[24576];
  const int t = threadIdx.x;
  const int lane = t & 63;
  const int wid = t >> 6;               // 0..7 = q-tile within group
  const int g = lane >> 4, ln = lane & 15;
  const int wg = ((blockIdx.x & 7) << 6) + (blockIdx.x >> 3);  // XCD: b = wg>>6
  const int b = wg >> 6;
  const int rem = wg & 63;
  const int h = rem >> 3;               // head (shared by whole block)
  const int qg = rem & 7;
  const int qt = qg * 8 + wid;          // this wave's q-tile
  const int q0 = qt << 4;

  char* K0 = smem;            // [32 k][128B] swizzled, shared
  char* K1 = smem + 4096;
  char* V0 = smem + 8192;     // [64 d][64B] swizzled, shared
  char* V1 = smem + 12288;
  char* Ps = smem + 16384 + wid * 1024;  // per-wave P round-trip

  // Q A-frags: row = ln, k-dim = ks*32 + g*8 + j (prescaled by log2e/8)
  bf16x8 qf[2];
#pragma unroll
  for (int ks = 0; ks < 2; ++ks)
    qf[ks] = *(const bf16x8*)(qk + ((size_t)b * 1024 + q0 + ln) * 1024 +
                              h * 64 + ks * 32 + g * 8);

  float l_acc[4] = {0.f, 0.f, 0.f, 0.f};
  f32x4 o_acc[4] = {};

  const int krow = lane >> 3;
  const int ksrc = ((lane & 7) * 16) ^ (krow << 4);
  const int vrow = lane >> 2;
  const int vsrc = ((lane & 3) * 16) ^ ((vrow & 3) << 4);

  const char* qkb = (const char*)qk + (size_t)b * 1024 * 2048;
  const char* vTb = (const char*)vT + (size_t)(b * 8 + h) * 64 * 2048;
  const _Float16* ebp = ebT + (size_t)((b * 64 + qt) * 32) * 512 + lane * 8;

  // cooperative stage of tile kt: wave wid contributes exactly ONE gl_lds.
  // waves 0-3: K rows [8w, 8w+8); waves 4-7: V d-rows [16(w-4), 16(w-4)+16).
  auto stage = [&](int kt, char* Kd, char* Vd) {
    if (wid < 4) {
      async_load16(qkb + (size_t)(kt * 32 + wid * 8 + krow) * 2048 + 1024 + h * 128 + ksrc,
                   Kd + wid * 1024 + lane * 16);
    } else {
      int c = wid - 4;
      async_load16(vTb + (size_t)(c * 16 + vrow) * 2048 + (size_t)(kt * 32) * 2 + vsrc,
                   Vd + c * 1024 + lane * 16);
    }
  };

  // prologue: tile 0 into buf0; eb(0) to regs; drain; barrier
  stage(0, K0, V0);
  f16x8 ebc = *(const f16x8*)(ebp);
  asm volatile("s_waitcnt vmcnt(0)" ::: "memory");
  __syncthreads();

  for (int kt = 0; kt < 32; ++kt) {
    char* Kp = (kt & 1) ? K1 : K0;
    char* Vp = (kt & 1) ? V1 : V0;
    char* Kn = (kt & 1) ? K0 : K1;
    char* Vn = (kt & 1) ? V0 : V1;
    const int ktn = (kt + 1) & 31;  // wrapped prefetch target

    // [1] issue next-tile staging (1 gl_lds) + eb(t+1) register load
    stage(ktn, Kn, Vn);
    f16x8 ebn = *(const f16x8*)(ebp + (size_t)ktn * 512);
    __builtin_amdgcn_sched_barrier(0);

    // [2] frag reads of tile t from shared buffers
    bf16x8 kf[2][2];
#pragma unroll
    for (int ni = 0; ni < 2; ++ni) {
      int br = ni * 16 + ln;
      int sw = (br & 7) << 4;
#pragma unroll
      for (int ks = 0; ks < 2; ++ks)
        kf[ni][ks] = *(const bf16x8*)(Kp + br * 128 + ((ks * 64 + g * 16) ^ sw));
    }
    bf16x8 vf[4];
#pragma unroll
    for (int di = 0; di < 4; ++di)
      vf[di] = *(const bf16x8*)(Vp + (di * 16 + ln) * 64 + ((g * 16) ^ ((ln & 3) << 4)));

    // [3] S = QK^T + bias via C-operand (D: q = 4g + r, key = ni*16 + ln)
    f32x4 lbf0 = {(float)ebc[0], (float)ebc[1], (float)ebc[2], (float)ebc[3]};
    f32x4 lbf1 = {(float)ebc[4], (float)ebc[5], (float)ebc[6], (float)ebc[7]};
    f32x4 s[2];
    s[0] = __builtin_amdgcn_mfma_f32_16x16x32_bf16(qf[0], kf[0][0], lbf0, 0, 0, 0);
    s[0] = __builtin_amdgcn_mfma_f32_16x16x32_bf16(qf[1], kf[0][1], s[0], 0, 0, 0);
    s[1] = __builtin_amdgcn_mfma_f32_16x16x32_bf16(qf[0], kf[1][0], lbf1, 0, 0, 0);
    s[1] = __builtin_amdgcn_mfma_f32_16x16x32_bf16(qf[1], kf[1][1], s[1], 0, 0, 0);

    // p = 2^s; accumulate l; P round-trip through wave-private LDS
#pragma unroll
    for (int r = 0; r < 4; ++r) {
      float p0 = fast_exp2(s[0][r]);
      float p1 = fast_exp2(s[1][r]);
      s[0][r] = p0; s[1][r] = p1;
      l_acc[r] += p0 + p1;
    }
#pragma unroll
    for (int ni = 0; ni < 2; ++ni)
#pragma unroll
      for (int r = 0; r < 4; ++r) {
        int q = g * 4 + r;
        *(__bf16*)(Ps + q * 64 + ((ni * 32 + ln * 2) ^ (((q >> 1) & 3) << 4))) =
            (__bf16)s[ni][r];
      }
    bf16x8 pf = *(const bf16x8*)(Ps + ln * 64 + ((g * 16) ^ (((ln >> 1) & 3) << 4)));

    // O += P V
#pragma unroll
    for (int di = 0; di < 4; ++di)
      o_acc[di] = __builtin_amdgcn_mfma_f32_16x16x32_bf16(pf, vf[di], o_acc[di], 0, 0, 0);

    // [4] drain own VMEM (1 gl_lds + eb load, issued a full compute ago);
    //     barrier publishes buf(t+1) to all waves.
    asm volatile("s_waitcnt vmcnt(0)" ::: "memory");
    __syncthreads();
    ebc = ebn;
  }

  // reduce l over the 16 ln-lanes, normalize, store
#pragma unroll
  for (int r = 0; r < 4; ++r) {
    float rs = l_acc[r];
#pragma unroll
    for (int off = 1; off < 16; off <<= 1)
      rs += __shfl_xor(rs, off, 64);
    float inv = 1.f / rs;
    int q = q0 + g * 4 + r;
#pragma unroll
    for (int di = 0; di < 4; ++di)
      attn[((size_t)b * 1024 + q) * 512 + h * 64 + di * 16 + ln] =
          (__bf16)(o_acc[di][r] * inv);
  }
}

extern "C" void kernel_launch(void* const* d_in, const int* in_sizes, int n_in,
                              void* d_out, int out_size, void* d_ws, size_t ws_size,
                              hipStream_t stream) {
  const float* x     = (const float*)d_in[0];
  const float* gb    = (const float*)d_in[1];
  const float* w_in  = (const float*)d_in[2];
  const float* b_in  = (const float*)d_in[3];
  const float* w_out = (const float*)d_in[4];
  const float* b_out = (const float*)d_in[5];
  const float* bstr  = (const float*)d_in[6];

  char* ws = (char*)d_ws;
  __bf16* qk    = (__bf16*)(ws);                      // 16,777,216 B
  __bf16* vT    = (__bf16*)(ws + 16777216);           //  8,388,608 B
  __bf16* xb    = (__bf16*)(ws + 25165824);           //  8,388,608 B
  __bf16* w1    = (__bf16*)(ws + 33554432);           //  1,572,864 B
  __bf16* w2    = (__bf16*)(ws + 35127296);           //    524,288 B
  _Float16* ebT = (_Float16*)(ws + 35651584);         // 16,777,216 B
  __bf16* attn_buf = xb;  // alias: x_bf16 dead after GEMM1

  cvt3<<<2560, 256, 0, stream>>>(x, xb, (8 * 1024 * 512) / 4,
                                 w_in, w1, (1536 * 512) / 4,
                                 w_out, w2, (512 * 512) / 4);
  build_ebias<<<4096, 256, 0, stream>>>(gb, bstr, ebT);

  gemm_bt<1><<<dim3(12, 64), 256, 0, stream>>>(xb, w1, b_in, qk, vT, 8192, 1536, 512);
  attn_fused<<<512, 512, 0, stream>>>(qk, vT, ebT, attn_buf);
  gemm_bt<0><<<dim3(4, 64), 256, 0, stream>>>(attn_buf, w2, b_out, d_out, nullptr, 8192, 512, 512);
}

// Round 13
// 96.625 us; speedup vs baseline: 1.5140x; 1.5140x over previous
//
#include <hip/hip_runtime.h>

typedef __attribute__((ext_vector_type(8))) __bf16 bf16x8;
typedef __attribute__((ext_vector_type(4))) __bf16 bf16x4;
typedef __attribute__((ext_vector_type(4))) float f32x4;
typedef __attribute__((ext_vector_type(8))) _Float16 f16x8;

#define LOG2E 1.44269504088896340736f

__device__ __forceinline__ void async_load16(const void* g, void* l) {
  __builtin_amdgcn_global_load_lds(
      (const __attribute__((address_space(1))) void*)g,
      (__attribute__((address_space(3))) void*)l, 16, 0, 0);
}

__device__ __forceinline__ float fast_exp2(float x) {
#if __has_builtin(__builtin_amdgcn_exp2f)
  return __builtin_amdgcn_exp2f(x);
#else
  return __expf(x * 0.6931471805599453f);
#endif
}

// ---------------- fp32 -> bf16 convert, 3 segments in one launch ----------
__global__ void cvt3(const float* __restrict__ a, __bf16* __restrict__ oa, int na4,
                     const float* __restrict__ b, __bf16* __restrict__ ob, int nb4,
                     const float* __restrict__ c, __bf16* __restrict__ oc, int nc4) {
  int i = blockIdx.x * blockDim.x + threadIdx.x;
  int n = na4 + nb4 + nc4;
  int stride = gridDim.x * blockDim.x;
  for (; i < n; i += stride) {
    const float4* s;
    bf16x4* d;
    int j;
    if (i < na4) { s = (const float4*)a; d = (bf16x4*)oa; j = i; }
    else if (i < na4 + nb4) { s = (const float4*)b; d = (bf16x4*)ob; j = i - na4; }
    else { s = (const float4*)c; d = (bf16x4*)oc; j = i - na4 - nb4; }
    float4 v = s[j];
    bf16x4 o;
    o[0] = (__bf16)v.x; o[1] = (__bf16)v.y; o[2] = (__bf16)v.z; o[3] = (__bf16)v.w;
    d[j] = o;
  }
}

// ---------------- log2-domain bias table, per-lane fragment layout ----------
// ebT f16x8 index (((b*64+qt)*32+kt)*64 + lane); element [ni*4+r] =
//   (sigmoid(gbias[b][kt*32+16ni+ln][qt*16+4g+r]) - 0.5) * 10*alpha*log2e
__global__ __launch_bounds__(256) void build_ebias(
    const float* __restrict__ gbias, const float* __restrict__ bstr,
    _Float16* __restrict__ ebT) {
  const int gid = blockIdx.x * 256 + threadIdx.x;  // 4096 blocks
  const int lane = gid & 63;
  const int kt = (gid >> 6) & 31;
  const int qt = (gid >> 11) & 63;
  const int b = gid >> 17;
  const int g = lane >> 4, ln = lane & 15;
  const float alpha = 1.f / (1.f + __expf(-bstr[0]));
  const float bsc = 10.f * alpha * LOG2E;
  const float* base = gbias + (size_t)(b * 1024 + kt * 32 + ln) * 1024 + qt * 16 + g * 4;
  float4 va = *(const float4*)(base);                  // ni=0 row
  float4 vb = *(const float4*)(base + 16 * 1024);      // ni=1 row
  float sv[8] = {va.x, va.y, va.z, va.w, vb.x, vb.y, vb.z, vb.w};
  f16x8 o;
#pragma unroll
  for (int i = 0; i < 8; ++i)
    o[i] = (_Float16)((1.f / (1.f + __expf(-sv[i])) - 0.5f) * bsc);
  *(f16x8*)(ebT + (size_t)gid * 8) = o;
}

// ---------------- C = (A @ Bm^T + bias) [*scale] ----------------
template <int MODE>
__global__ __launch_bounds__(256) void gemm_bt(
    const __bf16* __restrict__ A, const __bf16* __restrict__ Bm,
    const float* __restrict__ bias, void* __restrict__ C0,
    __bf16* __restrict__ vT, int M, int N, int K) {
  __shared__ __align__(16) char smem[32768];
  char* lA = smem;
  char* lB = smem + 16384;
  const int t = threadIdx.x;
  const int lane = t & 63;
  const int wid = t >> 6;
  const int wm = wid >> 1, wn = wid & 1;
  const int g = lane >> 4, ln = lane & 15;
  const int m0 = blockIdx.y * 128;
  const int n0 = blockIdx.x * 128;

  const int srow = t >> 3;
  const int sswz = ((t & 7) * 16) ^ ((srow & 7) << 4);
  const size_t KB = (size_t)K * 2;
  const char* gA = (const char*)A + (size_t)m0 * KB;
  const char* gB = (const char*)Bm + (size_t)n0 * KB;

  f32x4 acc[4][4] = {};

  for (int k0 = 0; k0 < K; k0 += 64) {
    __syncthreads();
#pragma unroll
    for (int c = 0; c < 4; ++c) {
      int row = srow + 32 * c;
      async_load16(gA + (size_t)row * KB + k0 * 2 + sswz, lA + c * 4096 + t * 16);
      async_load16(gB + (size_t)row * KB + k0 * 2 + sswz, lB + c * 4096 + t * 16);
    }
    __syncthreads();
#pragma unroll
    for (int ks = 0; ks < 2; ++ks) {
      bf16x8 af[4], bf[4];
#pragma unroll
      for (int i = 0; i < 4; ++i) {
        int ar = wm * 64 + i * 16 + ln;
        int byo = (ks * 64 + g * 16) ^ ((ar & 7) << 4);
        af[i] = *(const bf16x8*)(lA + ar * 128 + byo);
        int br = wn * 64 + i * 16 + ln;
        bf[i] = *(const bf16x8*)(lB + br * 128 + byo);
      }
#pragma unroll
      for (int i = 0; i < 4; ++i)
#pragma unroll
        for (int j = 0; j < 4; ++j)
          acc[i][j] = __builtin_amdgcn_mfma_f32_16x16x32_bf16(af[i], bf[j], acc[i][j], 0, 0, 0);
    }
  }

#pragma unroll
  for (int j = 0; j < 4; ++j) {
    int col = n0 + wn * 64 + j * 16 + ln;
    float bv = bias[col];
    if (MODE == 0) {
#pragma unroll
      for (int i = 0; i < 4; ++i) {
        int row0 = m0 + wm * 64 + i * 16 + g * 4;
#pragma unroll
        for (int r = 0; r < 4; ++r)
          ((float*)C0)[(size_t)(row0 + r) * N + col] = acc[i][j][r] + bv;
      }
    } else if (col < 1024) {
      float scale = (col < 512) ? (0.125f * LOG2E) : 1.0f;
#pragma unroll
      for (int i = 0; i < 4; ++i) {
        int row0 = m0 + wm * 64 + i * 16 + g * 4;
#pragma unroll
        for (int r = 0; r < 4; ++r)
          ((__bf16*)C0)[(size_t)(row0 + r) * 1024 + col] = (__bf16)((acc[i][j][r] + bv) * scale);
      }
    } else {
      int h = (col - 1024) >> 6;
      int d = (col - 1024) & 63;
#pragma unroll
      for (int i = 0; i < 4; ++i) {
        int row0 = m0 + wm * 64 + i * 16 + g * 4;
        int b = row0 >> 10;
        bf16x4 pk;
#pragma unroll
        for (int r = 0; r < 4; ++r) pk[r] = (__bf16)(acc[i][j][r] + bv);
        *(bf16x4*)(vT + (((size_t)b * 8 + h) * 64 + d) * 1024 + (row0 & 1023)) = pk;
      }
    }
  }
}

// ---------------- fused flash attention: block-cooperative shared K/V -----
// 512 blocks = (b, h, qg): 8 waves = 8 q-tiles of ONE head. K/V staged
// cooperatively (1 gl_lds per wave per iter: cuts the L2 re-read that made
// per-wave staging ~2300cy/iter/CU), double-buffered shared LDS; eb per-wave
// register load. Stage issued FIRST, drained LAST. launch_bounds(512,4):
// VGPR cap 128 -- R12's (512,8) forced 32 VGPRs and ~27MB/dispatch of
// scratch spill (WRITE_SIZE 34.8MB), which was the entire regression.
__global__ __launch_bounds__(512, 4) void attn_fused(
    const __bf16* __restrict__ qk,    // [B][N][1024]: q(log2-prescaled)|k
    const __bf16* __restrict__ vT,    // [B*8][64 d][1024 k]
    const _Float16* __restrict__ ebT, // f16 bias table
    __bf16* __restrict__ attn) {      // [B][N][512]
  __shared__ __align__(16) char smem[24576];
  const int t = threadIdx.x;
  const int lane = t & 63;
  const int wid = t >> 6;               // 0..7 = q-tile within group
  const int g = lane >> 4, ln = lane & 15;
  const int wg = ((blockIdx.x & 7) << 6) + (blockIdx.x >> 3);  // XCD: b = wg>>6
  const int b = wg >> 6;
  const int rem = wg & 63;
  const int h = rem >> 3;               // head (shared by whole block)
  const int qg = rem & 7;
  const int qt = qg * 8 + wid;          // this wave's q-tile
  const int q0 = qt << 4;

  char* K0 = smem;            // [32 k][128B] swizzled, shared
  char* K1 = smem + 4096;
  char* V0 = smem + 8192;     // [64 d][64B] swizzled, shared
  char* V1 = smem + 12288;
  char* Ps = smem + 16384 + wid * 1024;  // per-wave P round-trip

  // Q A-frags: row = ln, k-dim = ks*32 + g*8 + j (prescaled by log2e/8)
  bf16x8 qf[2];
#pragma unroll
  for (int ks = 0; ks < 2; ++ks)
    qf[ks] = *(const bf16x8*)(qk + ((size_t)b * 1024 + q0 + ln) * 1024 +
                              h * 64 + ks * 32 + g * 8);

  float l_acc[4] = {0.f, 0.f, 0.f, 0.f};
  f32x4 o_acc[4] = {};

  const int krow = lane >> 3;
  const int ksrc = ((lane & 7) * 16) ^ (krow << 4);
  const int vrow = lane >> 2;
  const int vsrc = ((lane & 3) * 16) ^ ((vrow & 3) << 4);

  const char* qkb = (const char*)qk + (size_t)b * 1024 * 2048;
  const char* vTb = (const char*)vT + (size_t)(b * 8 + h) * 64 * 2048;
  const _Float16* ebp = ebT + (size_t)((b * 64 + qt) * 32) * 512 + lane * 8;

  // cooperative stage of tile kt: wave wid contributes exactly ONE gl_lds.
  // waves 0-3: K rows [8w, 8w+8); waves 4-7: V d-rows [16(w-4), 16(w-4)+16).
  auto stage = [&](int kt, char* Kd, char* Vd) {
    if (wid < 4) {
      async_load16(qkb + (size_t)(kt * 32 + wid * 8 + krow) * 2048 + 1024 + h * 128 + ksrc,
                   Kd + wid * 1024 + lane * 16);
    } else {
      int c = wid - 4;
      async_load16(vTb + (size_t)(c * 16 + vrow) * 2048 + (size_t)(kt * 32) * 2 + vsrc,
                   Vd + c * 1024 + lane * 16);
    }
  };

  // prologue: tile 0 into buf0; eb(0) to regs; drain; barrier
  stage(0, K0, V0);
  f16x8 ebc = *(const f16x8*)(ebp);
  asm volatile("s_waitcnt vmcnt(0)" ::: "memory");
  __syncthreads();

  for (int kt = 0; kt < 32; ++kt) {
    char* Kp = (kt & 1) ? K1 : K0;
    char* Vp = (kt & 1) ? V1 : V0;
    char* Kn = (kt & 1) ? K0 : K1;
    char* Vn = (kt & 1) ? V0 : V1;
    const int ktn = (kt + 1) & 31;  // wrapped prefetch target

    // [1] issue next-tile staging (1 gl_lds) + eb(t+1) register load
    stage(ktn, Kn, Vn);
    f16x8 ebn = *(const f16x8*)(ebp + (size_t)ktn * 512);
    __builtin_amdgcn_sched_barrier(0);

    // [2] frag reads of tile t from shared buffers
    bf16x8 kf[2][2];
#pragma unroll
    for (int ni = 0; ni < 2; ++ni) {
      int br = ni * 16 + ln;
      int sw = (br & 7) << 4;
#pragma unroll
      for (int ks = 0; ks < 2; ++ks)
        kf[ni][ks] = *(const bf16x8*)(Kp + br * 128 + ((ks * 64 + g * 16) ^ sw));
    }
    bf16x8 vf[4];
#pragma unroll
    for (int di = 0; di < 4; ++di)
      vf[di] = *(const bf16x8*)(Vp + (di * 16 + ln) * 64 + ((g * 16) ^ ((ln & 3) << 4)));

    // [3] S = QK^T + bias via C-operand (D: q = 4g + r, key = ni*16 + ln)
    f32x4 lbf0 = {(float)ebc[0], (float)ebc[1], (float)ebc[2], (float)ebc[3]};
    f32x4 lbf1 = {(float)ebc[4], (float)ebc[5], (float)ebc[6], (float)ebc[7]};
    f32x4 s[2];
    s[0] = __builtin_amdgcn_mfma_f32_16x16x32_bf16(qf[0], kf[0][0], lbf0, 0, 0, 0);
    s[0] = __builtin_amdgcn_mfma_f32_16x16x32_bf16(qf[1], kf[0][1], s[0], 0, 0, 0);
    s[1] = __builtin_amdgcn_mfma_f32_16x16x32_bf16(qf[0], kf[1][0], lbf1, 0, 0, 0);
    s[1] = __builtin_amdgcn_mfma_f32_16x16x32_bf16(qf[1], kf[1][1], s[1], 0, 0, 0);

    // p = 2^s; accumulate l; P round-trip through wave-private LDS
#pragma unroll
    for (int r = 0; r < 4; ++r) {
      float p0 = fast_exp2(s[0][r]);
      float p1 = fast_exp2(s[1][r]);
      s[0][r] = p0; s[1][r] = p1;
      l_acc[r] += p0 + p1;
    }
#pragma unroll
    for (int ni = 0; ni < 2; ++ni)
#pragma unroll
      for (int r = 0; r < 4; ++r) {
        int q = g * 4 + r;
        *(__bf16*)(Ps + q * 64 + ((ni * 32 + ln * 2) ^ (((q >> 1) & 3) << 4))) =
            (__bf16)s[ni][r];
      }
    bf16x8 pf = *(const bf16x8*)(Ps + ln * 64 + ((g * 16) ^ (((ln >> 1) & 3) << 4)));

    // O += P V
#pragma unroll
    for (int di = 0; di < 4; ++di)
      o_acc[di] = __builtin_amdgcn_mfma_f32_16x16x32_bf16(pf, vf[di], o_acc[di], 0, 0, 0);

    // [4] drain own VMEM (1 gl_lds + eb load, issued a full compute ago);
    //     barrier publishes buf(t+1) to all waves.
    asm volatile("s_waitcnt vmcnt(0)" ::: "memory");
    __syncthreads();
    ebc = ebn;
  }

  // reduce l over the 16 ln-lanes, normalize, store
#pragma unroll
  for (int r = 0; r < 4; ++r) {
    float rs = l_acc[r];
#pragma unroll
    for (int off = 1; off < 16; off <<= 1)
      rs += __shfl_xor(rs, off, 64);
    float inv = 1.f / rs;
    int q = q0 + g * 4 + r;
#pragma unroll
    for (int di = 0; di < 4; ++di)
      attn[((size_t)b * 1024 + q) * 512 + h * 64 + di * 16 + ln] =
          (__bf16)(o_acc[di][r] * inv);
  }
}

extern "C" void kernel_launch(void* const* d_in, const int* in_sizes, int n_in,
                              void* d_out, int out_size, void* d_ws, size_t ws_size,
                              hipStream_t stream) {
  const float* x     = (const float*)d_in[0];
  const float* gb    = (const float*)d_in[1];
  const float* w_in  = (const float*)d_in[2];
  const float* b_in  = (const float*)d_in[3];
  const float* w_out = (const float*)d_in[4];
  const float* b_out = (const float*)d_in[5];
  const float* bstr  = (const float*)d_in[6];

  char* ws = (char*)d_ws;
  __bf16* qk    = (__bf16*)(ws);                      // 16,777,216 B
  __bf16* vT    = (__bf16*)(ws + 16777216);           //  8,388,608 B
  __bf16* xb    = (__bf16*)(ws + 25165824);           //  8,388,608 B
  __bf16* w1    = (__bf16*)(ws + 33554432);           //  1,572,864 B
  __bf16* w2    = (__bf16*)(ws + 35127296);           //    524,288 B
  _Float16* ebT = (_Float16*)(ws + 35651584);         // 16,777,216 B
  __bf16* attn_buf = xb;  // alias: x_bf16 dead after GEMM1

  cvt3<<<2560, 256, 0, stream>>>(x, xb, (8 * 1024 * 512) / 4,
                                 w_in, w1, (1536 * 512) / 4,
                                 w_out, w2, (512 * 512) / 4);
  build_ebias<<<4096, 256, 0, stream>>>(gb, bstr, ebT);

  gemm_bt<1><<<dim3(12, 64), 256, 0, stream>>>(xb, w1, b_in, qk, vT, 8192, 1536, 512);
  attn_fused<<<512, 512, 0, stream>>>(qk, vT, ebT, attn_buf);
  gemm_bt<0><<<dim3(4, 64), 256, 0, stream>>>(attn_buf, w2, b_out, d_out, nullptr, 8192, 512, 512);
}

// Round 14
// 96.164 us; speedup vs baseline: 1.5212x; 1.0048x over previous
//
#include <hip/hip_runtime.h>

typedef __attribute__((ext_vector_type(8))) __bf16 bf16x8;
typedef __attribute__((ext_vector_type(4))) __bf16 bf16x4;
typedef __attribute__((ext_vector_type(4))) float f32x4;
typedef __attribute__((ext_vector_type(8))) _Float16 f16x8;

#define LOG2E 1.44269504088896340736f

__device__ __forceinline__ void async_load16(const void* g, void* l) {
  __builtin_amdgcn_global_load_lds(
      (const __attribute__((address_space(1))) void*)g,
      (__attribute__((address_space(3))) void*)l, 16, 0, 0);
}

__device__ __forceinline__ float fast_exp2(float x) {
#if __has_builtin(__builtin_amdgcn_exp2f)
  return __builtin_amdgcn_exp2f(x);
#else
  return __expf(x * 0.6931471805599453f);
#endif
}

// ---------------- fp32 -> bf16 convert, 3 segments in one launch ----------
__global__ void cvt3(const float* __restrict__ a, __bf16* __restrict__ oa, int na4,
                     const float* __restrict__ b, __bf16* __restrict__ ob, int nb4,
                     const float* __restrict__ c, __bf16* __restrict__ oc, int nc4) {
  int i = blockIdx.x * blockDim.x + threadIdx.x;
  int n = na4 + nb4 + nc4;
  int stride = gridDim.x * blockDim.x;
  for (; i < n; i += stride) {
    const float4* s;
    bf16x4* d;
    int j;
    if (i < na4) { s = (const float4*)a; d = (bf16x4*)oa; j = i; }
    else if (i < na4 + nb4) { s = (const float4*)b; d = (bf16x4*)ob; j = i - na4; }
    else { s = (const float4*)c; d = (bf16x4*)oc; j = i - na4 - nb4; }
    float4 v = s[j];
    bf16x4 o;
    o[0] = (__bf16)v.x; o[1] = (__bf16)v.y; o[2] = (__bf16)v.z; o[3] = (__bf16)v.w;
    d[j] = o;
  }
}

// ---------------- log2-domain bias table, per-lane fragment layout ----------
// ebT f16x8 index (((b*64+qt)*32+kt)*64 + lane); element [ni*4+r] =
//   (sigmoid(gbias[b][kt*32+16ni+ln][qt*16+4g+r]) - 0.5) * 10*alpha*log2e
__global__ __launch_bounds__(256) void build_ebias(
    const float* __restrict__ gbias, const float* __restrict__ bstr,
    _Float16* __restrict__ ebT) {
  const int gid = blockIdx.x * 256 + threadIdx.x;  // 4096 blocks
  const int lane = gid & 63;
  const int kt = (gid >> 6) & 31;
  const int qt = (gid >> 11) & 63;
  const int b = gid >> 17;
  const int g = lane >> 4, ln = lane & 15;
  const float alpha = 1.f / (1.f + __expf(-bstr[0]));
  const float bsc = 10.f * alpha * LOG2E;
  const float* base = gbias + (size_t)(b * 1024 + kt * 32 + ln) * 1024 + qt * 16 + g * 4;
  float4 va = *(const float4*)(base);                  // ni=0 row
  float4 vb = *(const float4*)(base + 16 * 1024);      // ni=1 row
  float sv[8] = {va.x, va.y, va.z, va.w, vb.x, vb.y, vb.z, vb.w};
  f16x8 o;
#pragma unroll
  for (int i = 0; i < 8; ++i)
    o[i] = (_Float16)((1.f / (1.f + __expf(-sv[i])) - 0.5f) * bsc);
  *(f16x8*)(ebT + (size_t)gid * 8) = o;
}

// ---------------- C = (A @ Bm^T + bias) [*scale] ----------------
template <int MODE>
__global__ __launch_bounds__(256) void gemm_bt(
    const __bf16* __restrict__ A, const __bf16* __restrict__ Bm,
    const float* __restrict__ bias, void* __restrict__ C0,
    __bf16* __restrict__ vT, int M, int N, int K) {
  __shared__ __align__(16) char smem[32768];
  char* lA = smem;
  char* lB = smem + 16384;
  const int t = threadIdx.x;
  const int lane = t & 63;
  const int wid = t >> 6;
  const int wm = wid >> 1, wn = wid & 1;
  const int g = lane >> 4, ln = lane & 15;
  const int m0 = blockIdx.y * 128;
  const int n0 = blockIdx.x * 128;

  const int srow = t >> 3;
  const int sswz = ((t & 7) * 16) ^ ((srow & 7) << 4);
  const size_t KB = (size_t)K * 2;
  const char* gA = (const char*)A + (size_t)m0 * KB;
  const char* gB = (const char*)Bm + (size_t)n0 * KB;

  f32x4 acc[4][4] = {};

  for (int k0 = 0; k0 < K; k0 += 64) {
    __syncthreads();
#pragma unroll
    for (int c = 0; c < 4; ++c) {
      int row = srow + 32 * c;
      async_load16(gA + (size_t)row * KB + k0 * 2 + sswz, lA + c * 4096 + t * 16);
      async_load16(gB + (size_t)row * KB + k0 * 2 + sswz, lB + c * 4096 + t * 16);
    }
    __syncthreads();
#pragma unroll
    for (int ks = 0; ks < 2; ++ks) {
      bf16x8 af[4], bf[4];
#pragma unroll
      for (int i = 0; i < 4; ++i) {
        int ar = wm * 64 + i * 16 + ln;
        int byo = (ks * 64 + g * 16) ^ ((ar & 7) << 4);
        af[i] = *(const bf16x8*)(lA + ar * 128 + byo);
        int br = wn * 64 + i * 16 + ln;
        bf[i] = *(const bf16x8*)(lB + br * 128 + byo);
      }
#pragma unroll
      for (int i = 0; i < 4; ++i)
#pragma unroll
        for (int j = 0; j < 4; ++j)
          acc[i][j] = __builtin_amdgcn_mfma_f32_16x16x32_bf16(af[i], bf[j], acc[i][j], 0, 0, 0);
    }
  }

#pragma unroll
  for (int j = 0; j < 4; ++j) {
    int col = n0 + wn * 64 + j * 16 + ln;
    float bv = bias[col];
    if (MODE == 0) {
#pragma unroll
      for (int i = 0; i < 4; ++i) {
        int row0 = m0 + wm * 64 + i * 16 + g * 4;
#pragma unroll
        for (int r = 0; r < 4; ++r)
          ((float*)C0)[(size_t)(row0 + r) * N + col] = acc[i][j][r] + bv;
      }
    } else if (col < 1024) {
      float scale = (col < 512) ? (0.125f * LOG2E) : 1.0f;
#pragma unroll
      for (int i = 0; i < 4; ++i) {
        int row0 = m0 + wm * 64 + i * 16 + g * 4;
#pragma unroll
        for (int r = 0; r < 4; ++r)
          ((__bf16*)C0)[(size_t)(row0 + r) * 1024 + col] = (__bf16)((acc[i][j][r] + bv) * scale);
      }
    } else {
      int h = (col - 1024) >> 6;
      int d = (col - 1024) & 63;
#pragma unroll
      for (int i = 0; i < 4; ++i) {
        int row0 = m0 + wm * 64 + i * 16 + g * 4;
        int b = row0 >> 10;
        bf16x4 pk;
#pragma unroll
        for (int r = 0; r < 4; ++r) pk[r] = (__bf16)(acc[i][j][r] + bv);
        *(bf16x4*)(vT + (((size_t)b * 8 + h) * 64 + d) * 1024 + (row0 & 1023)) = pk;
      }
    }
  }
}

// ---------------- fused flash attention: cooperative K/V + counted drain --
// R13 structure (512 blocks = (b,h,qg), 8 waves share one head's K/V,
// cooperative 1-gl_lds/wave staging, double-buffered shared LDS) with the
// vmcnt(0) drain replaced by a COUNTED drain: per iteration each wave issues
// exactly two VMEM ops in fenced order [stage K/V(t+1), eb(t+2)]. vmcnt(1)
// retires stage(t+1) (+ last iter's eb(t+1)) and leaves eb(t+2) in flight,
// so the HBM eb stream gets ~2 iterations of latency coverage and never
// blocks the barrier. No other VMEM ops exist in the loop -> count is exact.
__global__ __launch_bounds__(512, 4) void attn_fused(
    const __bf16* __restrict__ qk,    // [B][N][1024]: q(log2-prescaled)|k
    const __bf16* __restrict__ vT,    // [B*8][64 d][1024 k]
    const _Float16* __restrict__ ebT, // f16 bias table
    __bf16* __restrict__ attn) {      // [B][N][512]
  __shared__ __align__(16) char smem[24576];
  const int t = threadIdx.x;
  const int lane = t & 63;
  const int wid = t >> 6;               // 0..7 = q-tile within group
  const int g = lane >> 4, ln = lane & 15;
  const int wg = ((blockIdx.x & 7) << 6) + (blockIdx.x >> 3);  // XCD: b = wg>>6
  const int b = wg >> 6;
  const int rem = wg & 63;
  const int h = rem >> 3;               // head (shared by whole block)
  const int qg = rem & 7;
  const int qt = qg * 8 + wid;          // this wave's q-tile
  const int q0 = qt << 4;

  char* K0 = smem;            // [32 k][128B] swizzled, shared
  char* K1 = smem + 4096;
  char* V0 = smem + 8192;     // [64 d][64B] swizzled, shared
  char* V1 = smem + 12288;
  char* Ps = smem + 16384 + wid * 1024;  // per-wave P round-trip

  // Q A-frags: row = ln, k-dim = ks*32 + g*8 + j (prescaled by log2e/8)
  bf16x8 qf[2];
#pragma unroll
  for (int ks = 0; ks < 2; ++ks)
    qf[ks] = *(const bf16x8*)(qk + ((size_t)b * 1024 + q0 + ln) * 1024 +
                              h * 64 + ks * 32 + g * 8);

  float l_acc[4] = {0.f, 0.f, 0.f, 0.f};
  f32x4 o_acc[4] = {};

  const int krow = lane >> 3;
  const int ksrc = ((lane & 7) * 16) ^ (krow << 4);
  const int vrow = lane >> 2;
  const int vsrc = ((lane & 3) * 16) ^ ((vrow & 3) << 4);

  const char* qkb = (const char*)qk + (size_t)b * 1024 * 2048;
  const char* vTb = (const char*)vT + (size_t)(b * 8 + h) * 64 * 2048;
  const _Float16* ebp = ebT + (size_t)((b * 64 + qt) * 32) * 512 + lane * 8;

  // cooperative stage of tile kt: wave wid contributes exactly ONE gl_lds.
  // waves 0-3: K rows [8w, 8w+8); waves 4-7: V d-rows [16(w-4), 16(w-4)+16).
  auto stage = [&](int kt, char* Kd, char* Vd) {
    if (wid < 4) {
      async_load16(qkb + (size_t)(kt * 32 + wid * 8 + krow) * 2048 + 1024 + h * 128 + ksrc,
                   Kd + wid * 1024 + lane * 16);
    } else {
      int c = wid - 4;
      async_load16(vTb + (size_t)(c * 16 + vrow) * 2048 + (size_t)(kt * 32) * 2 + vsrc,
                   Vd + c * 1024 + lane * 16);
    }
  };

  // prologue: tile 0 into buf0; eb(0),eb(1) to regs; full drain; barrier
  stage(0, K0, V0);
  f16x8 ebc = *(const f16x8*)(ebp);
  f16x8 ebn = *(const f16x8*)(ebp + 512);
  asm volatile("s_waitcnt vmcnt(0)" ::: "memory");
  __syncthreads();

  for (int kt = 0; kt < 32; ++kt) {
    char* Kp = (kt & 1) ? K1 : K0;
    char* Vp = (kt & 1) ? V1 : V0;
    char* Kn = (kt & 1) ? K0 : K1;
    char* Vn = (kt & 1) ? V0 : V1;
    const int ktn = (kt + 1) & 31;  // next tile (wrapped)
    const int kt2 = (kt + 2) & 31;  // eb 2-ahead (wrapped)

    // [1] issue next-tile staging (1 gl_lds per wave), fenced
    stage(ktn, Kn, Vn);
    __builtin_amdgcn_sched_barrier(0);
    // [2] eb(t+2) register prefetch -- the op vmcnt(1) leaves in flight
    f16x8 ebn2 = *(const f16x8*)(ebp + (size_t)kt2 * 512);
    __builtin_amdgcn_sched_barrier(0);

    // [3] frag reads of tile t from shared buffers
    bf16x8 kf[2][2];
#pragma unroll
    for (int ni = 0; ni < 2; ++ni) {
      int br = ni * 16 + ln;
      int sw = (br & 7) << 4;
#pragma unroll
      for (int ks = 0; ks < 2; ++ks)
        kf[ni][ks] = *(const bf16x8*)(Kp + br * 128 + ((ks * 64 + g * 16) ^ sw));
    }
    bf16x8 vf[4];
#pragma unroll
    for (int di = 0; di < 4; ++di)
      vf[di] = *(const bf16x8*)(Vp + (di * 16 + ln) * 64 + ((g * 16) ^ ((ln & 3) << 4)));

    // S = QK^T + bias via C-operand (D: q = 4g + r, key = ni*16 + ln)
    f32x4 lbf0 = {(float)ebc[0], (float)ebc[1], (float)ebc[2], (float)ebc[3]};
    f32x4 lbf1 = {(float)ebc[4], (float)ebc[5], (float)ebc[6], (float)ebc[7]};
    f32x4 s[2];
    s[0] = __builtin_amdgcn_mfma_f32_16x16x32_bf16(qf[0], kf[0][0], lbf0, 0, 0, 0);
    s[0] = __builtin_amdgcn_mfma_f32_16x16x32_bf16(qf[1], kf[0][1], s[0], 0, 0, 0);
    s[1] = __builtin_amdgcn_mfma_f32_16x16x32_bf16(qf[0], kf[1][0], lbf1, 0, 0, 0);
    s[1] = __builtin_amdgcn_mfma_f32_16x16x32_bf16(qf[1], kf[1][1], s[1], 0, 0, 0);

    // p = 2^s; accumulate l; P round-trip through wave-private LDS
#pragma unroll
    for (int r = 0; r < 4; ++r) {
      float p0 = fast_exp2(s[0][r]);
      float p1 = fast_exp2(s[1][r]);
      s[0][r] = p0; s[1][r] = p1;
      l_acc[r] += p0 + p1;
    }
#pragma unroll
    for (int ni = 0; ni < 2; ++ni)
#pragma unroll
      for (int r = 0; r < 4; ++r) {
        int q = g * 4 + r;
        *(__bf16*)(Ps + q * 64 + ((ni * 32 + ln * 2) ^ (((q >> 1) & 3) << 4))) =
            (__bf16)s[ni][r];
      }
    bf16x8 pf = *(const bf16x8*)(Ps + ln * 64 + ((g * 16) ^ (((ln >> 1) & 3) << 4)));

    // O += P V
#pragma unroll
    for (int di = 0; di < 4; ++di)
      o_acc[di] = __builtin_amdgcn_mfma_f32_16x16x32_bf16(pf, vf[di], o_acc[di], 0, 0, 0);

    // [4] counted drain: VMEM order [..., eb(t+1), stage(t+1), eb(t+2)];
    //     vmcnt(1) retires stage(t+1) + eb(t+1), leaves eb(t+2) in flight.
    //     Barrier then publishes buf(t+1) to all waves.
    asm volatile("s_waitcnt vmcnt(1)" ::: "memory");
    __builtin_amdgcn_sched_barrier(0);
    __syncthreads();
    ebc = ebn;
    ebn = ebn2;
  }

  // reduce l over the 16 ln-lanes, normalize, store
#pragma unroll
  for (int r = 0; r < 4; ++r) {
    float rs = l_acc[r];
#pragma unroll
    for (int off = 1; off < 16; off <<= 1)
      rs += __shfl_xor(rs, off, 64);
    float inv = 1.f / rs;
    int q = q0 + g * 4 + r;
#pragma unroll
    for (int di = 0; di < 4; ++di)
      attn[((size_t)b * 1024 + q) * 512 + h * 64 + di * 16 + ln] =
          (__bf16)(o_acc[di][r] * inv);
  }
}

extern "C" void kernel_launch(void* const* d_in, const int* in_sizes, int n_in,
                              void* d_out, int out_size, void* d_ws, size_t ws_size,
                              hipStream_t stream) {
  const float* x     = (const float*)d_in[0];
  const float* gb    = (const float*)d_in[1];
  const float* w_in  = (const float*)d_in[2];
  const float* b_in  = (const float*)d_in[3];
  const float* w_out = (const float*)d_in[4];
  const float* b_out = (const float*)d_in[5];
  const float* bstr  = (const float*)d_in[6];

  char* ws = (char*)d_ws;
  __bf16* qk    = (__bf16*)(ws);                      // 16,777,216 B
  __bf16* vT    = (__bf16*)(ws + 16777216);           //  8,388,608 B
  __bf16* xb    = (__bf16*)(ws + 25165824);           //  8,388,608 B
  __bf16* w1    = (__bf16*)(ws + 33554432);           //  1,572,864 B
  __bf16* w2    = (__bf16*)(ws + 35127296);           //    524,288 B
  _Float16* ebT = (_Float16*)(ws + 35651584);         // 16,777,216 B
  __bf16* attn_buf = xb;  // alias: x_bf16 dead after GEMM1

  cvt3<<<2560, 256, 0, stream>>>(x, xb, (8 * 1024 * 512) / 4,
                                 w_in, w1, (1536 * 512) / 4,
                                 w_out, w2, (512 * 512) / 4);
  build_ebias<<<4096, 256, 0, stream>>>(gb, bstr, ebT);

  gemm_bt<1><<<dim3(12, 64), 256, 0, stream>>>(xb, w1, b_in, qk, vT, 8192, 1536, 512);
  attn_fused<<<512, 512, 0, stream>>>(qk, vT, ebT, attn_buf);
  gemm_bt<0><<<dim3(4, 64), 256, 0, stream>>>(attn_buf, w2, b_out, d_out, nullptr, 8192, 512, 512);
}